// Round 12
// baseline (392.340 us; speedup 1.0000x reference)
//
#include <hip/hip_runtime.h>
#include <cstdint>
#include <cstddef>

#define NEGV (-1e10f)

typedef short short8 __attribute__((ext_vector_type(8)));
typedef short short4_t __attribute__((ext_vector_type(4)));
typedef float f32x4 __attribute__((ext_vector_type(4)));
typedef long long2_t __attribute__((ext_vector_type(2)));

__device__ __forceinline__ float bf2f(short s) {
    union { float f; uint32_t u; } x;
    x.u = ((uint32_t)(uint16_t)s) << 16;
    return x.f;
}
__device__ __forceinline__ short f2bf(float f) {
    union { float f; uint32_t u; } x;
    x.f = f;
    uint32_t u = x.u;
    uint32_t r = (u + 0x7fffu + ((u >> 16) & 1u)) >> 16;
    return (short)r;
}

__device__ __forceinline__ void gl2lds16(const void* gsrc, void* ldst) {
    __builtin_amdgcn_global_load_lds(
        (const __attribute__((address_space(1))) void*)gsrc,
        (__attribute__((address_space(3))) void*)ldst, 16, 0, 0);
}

// pack 8 f32 -> 8 fp8(e4m3) bytes via HW cvt_pk
__device__ __forceinline__ void pack8_fp8(const float* pr, int* w0, int* w1) {
    int a = __builtin_amdgcn_cvt_pk_fp8_f32(pr[0], pr[1], 0, false);
    a = __builtin_amdgcn_cvt_pk_fp8_f32(pr[2], pr[3], a, true);
    int b = __builtin_amdgcn_cvt_pk_fp8_f32(pr[4], pr[5], 0, false);
    b = __builtin_amdgcn_cvt_pk_fp8_f32(pr[6], pr[7], b, true);
    *w0 = a; *w1 = b;
}

// ---------------------------------------------------------------------------
// bf16 GEMM core: C[M,N] = A[M,K] * BT[N,K]^T. 128x128 tile, BK=64, 4 waves,
// mfma_f32_16x16x32_bf16, XOR-rotated LDS granules (conflict-free, r3).
// epi: 0 = store f32, 1 = store bf16,
//      4 = store bf16 + bias (Cg[gid]+b1p) when z==0   (AB0 build)
// ---------------------------------------------------------------------------
__device__ __forceinline__ void gemm_core(
    int epi, const short* __restrict__ A, int lda,
    const short* __restrict__ BT, int ldb,
    void* __restrict__ Cout, int ldc, int K,
    int bn, int bm, int z, int zBT, int zC,
    const int* __restrict__ gid, const float* __restrict__ Cg,
    const float* __restrict__ b1p)
{
    __shared__ short As[128 * 64];
    __shared__ short Bs[128 * 64];

    const int tid = threadIdx.x;
    const int lane = tid & 63;
    const int w = tid >> 6;
    const int quad = lane >> 4;
    const int l15 = lane & 15;
    const int colz = z * zC;
    BT += (size_t)z * zBT;

    f32x4 acc[4][4];
#pragma unroll
    for (int mi = 0; mi < 4; mi++)
#pragma unroll
        for (int ni = 0; ni < 4; ni++)
            acc[mi][ni] = {0.f, 0.f, 0.f, 0.f};

    const int mb = (w >> 1) * 64, nb = (w & 1) * 64;
    const int r8 = lane >> 3;
    const int sg = ((lane & 7) - r8) & 7;

    for (int k0 = 0; k0 < K; k0 += 64) {
#pragma unroll
        for (int c = 0; c < 4; c++) {
            int chunk = w * 4 + c;
            int row = chunk * 8 + r8;
            gl2lds16(BT + (size_t)(bn * 128 + row) * ldb + k0 + sg * 8, Bs + chunk * 512);
            gl2lds16(A + (size_t)(bm * 128 + row) * lda + k0 + sg * 8, As + chunk * 512);
        }
        __syncthreads();
#pragma unroll
        for (int ks = 0; ks < 64; ks += 32) {
            short8 af[4], bfr[4];
            const int gb = quad + (ks >> 3);
#pragma unroll
            for (int mi = 0; mi < 4; mi++) {
                int row = mb + mi * 16 + l15;
                af[mi] = *(const short8*)(As + row * 64 + (((gb + row) & 7) << 3));
            }
#pragma unroll
            for (int ni = 0; ni < 4; ni++) {
                int row = nb + ni * 16 + l15;
                bfr[ni] = *(const short8*)(Bs + row * 64 + (((gb + row) & 7) << 3));
            }
#pragma unroll
            for (int mi = 0; mi < 4; mi++)
#pragma unroll
                for (int ni = 0; ni < 4; ni++)
                    acc[mi][ni] = __builtin_amdgcn_mfma_f32_16x16x32_bf16(
                        af[mi], bfr[ni], acc[mi][ni], 0, 0, 0);
        }
        __syncthreads();
    }

#pragma unroll
    for (int mi = 0; mi < 4; mi++)
#pragma unroll
        for (int ni = 0; ni < 4; ni++) {
            int col = bn * 128 + nb + ni * 16 + l15;
#pragma unroll
            for (int reg = 0; reg < 4; reg++) {
                int rowg = bm * 128 + mb + mi * 16 + quad * 4 + reg;
                float v = acc[mi][ni][reg];
                if (epi == 0) {
                    ((float*)Cout)[(size_t)rowg * ldc + col] = v;
                } else if (epi == 1) {
                    ((short*)Cout)[(size_t)rowg * ldc + col] = f2bf(v);
                } else {  // epi == 4
                    if (z == 0)
                        v += Cg[gid[rowg] * 1024 + col] + b1p[col];
                    ((short*)Cout)[(size_t)rowg * ldc + colz + col] = f2bf(v);
                }
            }
        }
}

template <int EPI>
__global__ __launch_bounds__(256) void gemm_bt(
    const short* __restrict__ A, int lda,
    const short* __restrict__ BT, int ldb,
    void* __restrict__ Cout, int ldc, int K,
    int zBT, int zC,
    const int* __restrict__ gid, const float* __restrict__ Cg,
    const float* __restrict__ b1p)
{
    gemm_core(EPI, A, lda, BT, ldb, Cout, ldc, K,
              blockIdx.x, blockIdx.y, blockIdx.z, zBT, zC, gid, Cg, b1p);
}

// pairprod body: 4 granules/thread, contiguous 8B stores
__device__ __forceinline__ void pairprod_body(
    int pb, int tid, const short* __restrict__ g_bf,
    const int* __restrict__ bjj, uint8_t* __restrict__ P)
{
#pragma unroll
    for (int it = 0; it < 4; it++) {
        int gidx = pb * 1024 + it * 256 + tid;
        if (gidx >= 51200 * 64) return;
        int p = gidx >> 6, g8 = gidx & 63;
        int i = p / 50;
        int j = bjj[p];
        short8 va = *(const short8*)(g_bf + (size_t)i * 512 + g8 * 8);
        short8 vb = *(const short8*)(g_bf + (size_t)j * 512 + g8 * 8);
        float pr[8];
#pragma unroll
        for (int e = 0; e < 8; e++) pr[e] = bf2f(va[e]) * bf2f(vb[e]);
        int2 out;
        pack8_fp8(pr, &out.x, &out.y);
        *(int2*)(P + (size_t)p * 512 + g8 * 8) = out;
    }
}

// Combined (all independent, all read g_bf):
//   [0,128)   AB0 GEMM (epi4, 2 z-halves)
//   [128,160) coarse1: tmp = g @ cW^T        (epi1)
//   [160,192) G1 = g @ Wf_top^T              (epi1)
//   [192,224) G2 = g @ Wf_bot^T              (epi1)
__global__ __launch_bounds__(256) void ab0_coarse1_kernel(
    const short* __restrict__ g_bf, const short* __restrict__ W1T,
    short* __restrict__ AB0bf, const short* __restrict__ cwbf,
    short* __restrict__ tmpbf, const short* __restrict__ WfT,
    short* __restrict__ G1bf, short* __restrict__ G2bf,
    const int* __restrict__ gid, const float* __restrict__ Cg,
    const float* __restrict__ b1p)
{
    int bx = blockIdx.x;
    if (bx < 128) {
        int z = bx >> 6, rem = bx & 63;
        gemm_core(4, g_bf, 512, W1T, 1536, AB0bf, 2048, 512,
                  rem & 7, rem >> 3, z, 512, 1024, gid, Cg, b1p);
    } else if (bx < 160) {
        int r = bx - 128;
        gemm_core(1, g_bf, 512, cwbf, 512, tmpbf, 512, 512,
                  r & 3, r >> 2, 0, 0, 0, nullptr, nullptr, nullptr);
    } else if (bx < 192) {
        int r = bx - 160;
        gemm_core(1, g_bf, 512, WfT, 1024, G1bf, 512, 512,
                  r & 3, r >> 2, 0, 0, 0, nullptr, nullptr, nullptr);
    } else {
        int r = bx - 192;
        gemm_core(1, g_bf, 512, WfT + 512, 1024, G2bf, 512, 512,
                  r & 3, r >> 2, 0, 0, 0, nullptr, nullptr, nullptr);
    }
}

// Combined: blocks [0,128) AB0 GEMM (epi4) from gnew, [128,3328) pairprod(gnew)
__global__ __launch_bounds__(256) void ab0_pairprod_kernel(
    const short* __restrict__ gnew, const short* __restrict__ W1T,
    short* __restrict__ AB0bf,
    const int* __restrict__ gid, const float* __restrict__ Cg,
    const float* __restrict__ b1p,
    const int* __restrict__ bjj, uint8_t* __restrict__ P)
{
    int bx = blockIdx.x;
    if (bx < 128) {
        int z = bx >> 6, rem = bx & 63;
        gemm_core(4, gnew, 512, W1T, 1536, AB0bf, 2048, 512,
                  rem & 7, rem >> 3, z, 512, 1024, gid, Cg, b1p);
    } else {
        pairprod_body(bx - 128, threadIdx.x, gnew, bjj, P);
    }
}

// ---------------------------------------------------------------------------
// Fused score GEMM, fp8 e4m3: 128 pairs x 128 hidden, K=512, BK=128.
// Grid (bn=8, bm=400): temporal co-scheduling shares P via L3; XCD x only
// sees bn==x -> W1c8 slab L2-resident. Comb bias staged to LDS; no global
// atomics. Do NOT grow this tile (r9: acc spill) or permute global layouts
// (r7: scattered producer stores).
// r12: fragment reads are paired-b128 with k-slot reassignment — phase h,
// quad q reads granule 2q+h (16B) feeding two MFMA steps. Valid because A
// and B use the IDENTICAL lane->k mapping (MFMA sums over k; internal slot
// order cancels). Removes the b64 off8 4-way bank conflicts.
// ---------------------------------------------------------------------------
__global__ __launch_bounds__(256, 4) void fused_score_kernel(
    const uint8_t* __restrict__ P,      // [51200][512] fp8
    const uint8_t* __restrict__ W1c8,   // [1024][512] fp8 (x16)
    const int* __restrict__ bjj,
    const int* __restrict__ fcode,
    const short* __restrict__ AB0bf,    // [1024][2048] bf16: A0 | B0
    const short* __restrict__ Ftabbf,   // [18][1024] bf16
    const float* __restrict__ w2p,      // [1024]
    float* __restrict__ sacc_part)      // [8][51200]
{
    __shared__ short U[16896];          // As(16K)|Bs(16K) bytes; reused comb[128][132]
    __shared__ int iL[128], jL[128], fcL[128];
    __shared__ float saccs[128];

    uint8_t* As = (uint8_t*)U;
    uint8_t* Bs = As + 16384;

    const int tid = threadIdx.x, lane = tid & 63, w = tid >> 6;
    const int quad = lane >> 4, l15 = lane & 15;
    const int bn = blockIdx.x, bm = blockIdx.y;
    const int mb = (w >> 1) * 64, nb = (w & 1) * 64;
    const int nbase = bn * 128;

    if (tid < 128) {
        int p = bm * 128 + tid;
        iL[tid] = p / 50;
        jL[tid] = bjj[p];
        fcL[tid] = fcode[p];
        saccs[tid] = 0.f;
    }
    __syncthreads();

    f32x4 acc[4][4];
#pragma unroll
    for (int mi = 0; mi < 4; mi++)
#pragma unroll
        for (int ni = 0; ni < 4; ni++)
            acc[mi][ni] = {0.f, 0.f, 0.f, 0.f};

    const int r8 = lane >> 3;
    const int sg = ((lane & 7) - r8) & 7;   // rotated 16B source granule

    for (int k0 = 0; k0 < 512; k0 += 128) {
#pragma unroll
        for (int c = 0; c < 4; c++) {
            int chunk = w * 4 + c;
            int row = chunk * 8 + r8;
            gl2lds16(W1c8 + (size_t)(nbase + row) * 512 + k0 + sg * 16, Bs + chunk * 1024);
            gl2lds16(P + (size_t)(bm * 128 + row) * 512 + k0 + sg * 16, As + chunk * 1024);
        }
        __syncthreads();
#pragma unroll
        for (int h = 0; h < 2; h++) {
            const int gb = (quad << 1) + h;
            long2_t a2[4];
#pragma unroll
            for (int mi = 0; mi < 4; mi++) {
                int row = mb + mi * 16 + l15;
                a2[mi] = *(const long2_t*)(As + row * 128 + (((gb + row) & 7) << 4));
            }
#pragma unroll
            for (int ni = 0; ni < 4; ni++) {
                int row = nb + ni * 16 + l15;
                long2_t b2 = *(const long2_t*)(Bs + row * 128 + (((gb + row) & 7) << 4));
#pragma unroll
                for (int mi = 0; mi < 4; mi++) {
                    acc[mi][ni] = __builtin_amdgcn_mfma_f32_16x16x32_fp8_fp8(
                        a2[mi][0], b2[0], acc[mi][ni], 0, 0, 0);
                    acc[mi][ni] = __builtin_amdgcn_mfma_f32_16x16x32_fp8_fp8(
                        a2[mi][1], b2[1], acc[mi][ni], 0, 0, 0);
                }
            }
        }
        __syncthreads();
    }

    // ---- stage combined bias comb[r][c] (bf16, stride 132) into U ----
    {
        int r = tid >> 1;
        int colb = (tid & 1) * 64;
        int i = iL[r], j = jL[r], fc = fcL[r];
        const short* pa = AB0bf + (size_t)i * 2048 + nbase + colb;
        const short* pb = AB0bf + (size_t)j * 2048 + 1024 + nbase + colb;
        const short* pf = Ftabbf + fc * 1024 + nbase + colb;
        short* dst = U + r * 132 + colb;
#pragma unroll
        for (int c8 = 0; c8 < 8; c8++) {
            short8 va = *(const short8*)(pa + c8 * 8);
            short8 vb = *(const short8*)(pb + c8 * 8);
            short8 vf = *(const short8*)(pf + c8 * 8);
            short4_t lo, hi;
#pragma unroll
            for (int e = 0; e < 4; e++)
                lo[e] = f2bf(bf2f(va[e]) + bf2f(vb[e]) + bf2f(vf[e]));
#pragma unroll
            for (int e = 0; e < 4; e++)
                hi[e] = f2bf(bf2f(va[e + 4]) + bf2f(vb[e + 4]) + bf2f(vf[e + 4]));
            *(short4_t*)(dst + c8 * 8) = lo;
            *(short4_t*)(dst + c8 * 8 + 4) = hi;
        }
    }
    __syncthreads();

    // ---- layer-2 epilogue: pure LDS ----
    float w2v[4];
#pragma unroll
    for (int ni = 0; ni < 4; ni++) w2v[ni] = w2p[nbase + nb + ni * 16 + l15];
#pragma unroll
    for (int mi = 0; mi < 4; mi++)
#pragma unroll
        for (int reg = 0; reg < 4; reg++) {
            int rloc = mb + mi * 16 + quad * 4 + reg;
            float s = 0.f;
#pragma unroll
            for (int ni = 0; ni < 4; ni++) {
                float pre = acc[mi][ni][reg] * 0.0625f + bf2f(U[rloc * 132 + nb + ni * 16 + l15]);
                s += fmaxf(pre, 0.f) * w2v[ni];
            }
#pragma unroll
            for (int m = 1; m < 16; m <<= 1) s += __shfl_xor(s, m);
            if (l15 == 0) atomicAdd(&saccs[rloc], s);
        }
    __syncthreads();
    if (tid < 128)
        sacc_part[(size_t)bn * 51200 + bm * 128 + tid] = saccs[tid];
}

// ---------------------------------------------------------------------------
// Unified prep.
// ---------------------------------------------------------------------------
__device__ __forceinline__ void transpose_tile(
    const float* __restrict__ src, short* __restrict__ dst,
    int ncolsPhys, int dstStride, int bx, int by, int t) {
    __shared__ float tile[64][65];
    const int kin0 = bx * 64, hh0 = by * 64;
#pragma unroll
    for (int r = 0; r < 16; r++) {
        int kin_l = r * 4 + (t >> 6);
        int hh_l = t & 63;
        int hh = hh0 + hh_l;
        float v = (hh < ncolsPhys) ? src[(size_t)(kin0 + kin_l) * ncolsPhys + hh] : 0.f;
        tile[kin_l][hh_l] = v;
    }
    __syncthreads();
#pragma unroll
    for (int r = 0; r < 16; r++) {
        int hh_l = r * 4 + (t >> 6);
        int kin_l = t & 63;
        dst[(size_t)(hh0 + hh_l) * dstStride + kin0 + kin_l] = f2bf(tile[kin_l][hh_l]);
    }
}

// W1c slice (kin in [1024,1536)) -> fp8 x16, dst[hh][kin-1024], ld 512
__device__ __forceinline__ void transpose_tile_fp8(
    const float* __restrict__ W1, uint8_t* __restrict__ dst,
    int bx, int by, int t) {
    __shared__ float tile8[64][65];
    const int kin0 = 1024 + bx * 64, hh0 = by * 64;
#pragma unroll
    for (int r = 0; r < 16; r++) {
        int kin_l = r * 4 + (t >> 6);
        int hh_l = t & 63;
        int hh = hh0 + hh_l;
        float v = (hh < 1000) ? W1[(size_t)(kin0 + kin_l) * 1000 + hh] : 0.f;
        tile8[kin_l][hh_l] = v;
    }
    __syncthreads();
#pragma unroll
    for (int r = 0; r < 16; r++) {
        int hh_l = r * 4 + (t >> 6);
        int kin_l = t & 63;
        float v = tile8[kin_l][hh_l] * 16.f;
        int pk = __builtin_amdgcn_cvt_pk_fp8_f32(v, 0.f, 0, false);
        dst[(size_t)(hh0 + hh_l) * 512 + bx * 64 + kin_l] = (uint8_t)(pk & 0xff);
    }
}

__global__ __launch_bounds__(256) void prep_all_kernel(
    const float* __restrict__ W1, const float* __restrict__ Wf,
    const float* __restrict__ cW, const float* __restrict__ W2,
    const float* __restrict__ b1, const float* __restrict__ genre_e,
    const float* __restrict__ dist_e, const float* __restrict__ spk_e,
    const float* __restrict__ g,
    short* W1T, short* WfT, uint8_t* W1c8, short* cwbf, float* w2p, float* b1p,
    float* Cg, short* Ftabbf, short* g_bf) {
    int b = blockIdx.x;
    int t = threadIdx.x;
    if (b < 384) { transpose_tile(W1, W1T, 1000, 1536, b % 24, b / 24, t); return; }
    if (b < 512) { int bb = b - 384; transpose_tile(Wf, WfT, 512, 1024, bb % 16, bb / 16, t); return; }
    if (b < 640) { int bb = b - 512; transpose_tile_fp8(W1, W1c8, bb % 8, bb / 8, t); return; }
    int idx = (b - 640) * 256 + t;
    if (idx < 512 * 512) { cwbf[idx] = f2bf(cW[idx]); return; }
    idx -= 512 * 512;
    if (idx < 1024) { w2p[idx] = (idx < 1000) ? W2[idx] : 0.f; return; }
    idx -= 1024;
    if (idx < 1024) { b1p[idx] = (idx < 1000) ? b1[idx] : 0.f; return; }
    idx -= 1024;
    if (idx < 8 * 1024) {
        int gg = idx >> 10, h = idx & 1023;
        float v = 0.f;
        if (h < 1000)
            for (int e = 0; e < 20; e++) v += genre_e[gg * 20 + e] * W1[(size_t)(1556 + e) * 1000 + h];
        Cg[idx] = v;
        return;
    }
    idx -= 8 * 1024;
    if (idx < 18 * 1024) {
        int code = idx >> 10, h = idx & 1023;
        int bb = code >> 1, s2 = code & 1;
        float v = 0.f;
        if (h < 1000) {
            for (int e = 0; e < 20; e++) v += dist_e[bb * 20 + e] * W1[(size_t)(1536 + e) * 1000 + h];
            for (int e = 0; e < 20; e++) v += spk_e[(s2 + 1) * 20 + e] * W1[(size_t)(1576 + e) * 1000 + h];
        }
        Ftabbf[idx] = f2bf(v);
        return;
    }
    idx -= 18 * 1024;
    if (idx < 1024 * 512) g_bf[idx] = f2bf(g[idx]);
}

// ---------------------------------------------------------------------------
// Exact top-50 per row + fused P fill (fp8, contiguous). Candidate mapping
// j = c*64 + lane -> coalesced ant reads. Wave 0 selects; all 4 waves fill.
// ---------------------------------------------------------------------------
__global__ __launch_bounds__(256) void topk_kernel(
    const float* __restrict__ ant, const float* __restrict__ ms,
    const int* __restrict__ sidx, const int* __restrict__ eidx,
    const int* __restrict__ spk, const short* __restrict__ g_bf,
    float* __restrict__ bscore, int* __restrict__ bjj, int* __restrict__ fcodes,
    uint8_t* __restrict__ P) {
    int i = blockIdx.x;
    int tid = threadIdx.x;
    __shared__ int bjL[50];
    if (tid < 64) {
        int lane = tid;
        float v[16];
        float si = ms[i];
#pragma unroll
        for (int c = 0; c < 16; c++) {
            int j = c * 64 + lane;
            float val = ant[(size_t)i * 1024 + j] + si + ms[j];
            v[c] = (j < i) ? val : (val + NEGV);
        }
        int ei = eidx[i];
        int spi = spk[i];
        for (int r = 0; r < 50; r++) {
            float bv = -3.4e38f;
            int bj = 1 << 30;
#pragma unroll
            for (int c = 0; c < 16; c++) {
                int j = c * 64 + lane;
                if (v[c] > bv) { bv = v[c]; bj = j; }
            }
#pragma unroll
            for (int m = 1; m < 64; m <<= 1) {
                float ov = __shfl_xor(bv, m);
                int oj = __shfl_xor(bj, m);
                if (ov > bv || (ov == bv && oj < bj)) { bv = ov; bj = oj; }
            }
            if (lane == 0) {
                bscore[i * 50 + r] = bv;
                bjj[i * 50 + r] = bj;
                bjL[r] = bj;
                int d = ei - sidx[bj];
                int bin = (d > 1) + (d > 2) + (d > 3) + (d > 4) + (d > 8) + (d > 16) + (d > 32) + (d > 64);
                int lab = (spi == spk[bj]) ? 0 : 1;
                fcodes[i * 50 + r] = bin * 2 + lab;
            }
#pragma unroll
            for (int c = 0; c < 16; c++)
                if (bj == c * 64 + lane) v[c] = -3.4e38f;
        }
    }
    __syncthreads();
    int g8 = tid & 63;
    short8 va = *(const short8*)(g_bf + (size_t)i * 512 + g8 * 8);
    for (int r = tid >> 6; r < 50; r += 4) {
        int j = bjL[r];
        short8 vb = *(const short8*)(g_bf + (size_t)j * 512 + g8 * 8);
        float pr[8];
#pragma unroll
        for (int e = 0; e < 8; e++) pr[e] = bf2f(va[e]) * bf2f(vb[e]);
        int2 out;
        pack8_fp8(pr, &out.x, &out.y);
        *(int2*)(P + (size_t)(i * 50 + r) * 512 + g8 * 8) = out;
    }
}

__device__ __forceinline__ float sum_parts(const float* __restrict__ sacc_part, int p,
                                           const float* __restrict__ b2,
                                           const float* __restrict__ bscore) {
    float s = b2[0] + bscore[p];
#pragma unroll
    for (int q = 0; q < 8; q++) s += sacc_part[(size_t)q * 51200 + p];
    return s;
}

// ---------------------------------------------------------------------------
// Softmax + full gate update in one kernel (gate GEMM eliminated, r11):
//   f_pre[i] = G1[i] + sum_c p_c * G2[cidx_c] + bf
//   gnew[i]  = f*g[i] + (1-f)*a_n,  a_n = sum_c p_c * g[cidx_c]
// r12: each thread handles 2 consecutive dims via dword gathers.
// ---------------------------------------------------------------------------
__global__ __launch_bounds__(256) void softmax_gate_kernel(
    const float* __restrict__ sacc_part, const float* __restrict__ b2,
    const float* __restrict__ bscore,
    const int* __restrict__ bjj, const short* __restrict__ g_bf,
    const short* __restrict__ G1bf, const short* __restrict__ G2bf,
    const float* __restrict__ bfv, short* __restrict__ gnew) {
    int i = blockIdx.x;
    int tid = threadIdx.x;
    if (i == 0) {  // span 0 never refined
        ((int*)gnew)[tid] = ((const int*)g_bf)[tid];
        return;
    }
    __shared__ float pw[64];
    __shared__ int cidx[51];
    if (tid < 64) {
        int c = tid;
        float val;
        if (c == 0) { val = 0.f; cidx[0] = i; }
        else if (c < 51) {
            int kk = c - 1;
            int vc = (i < 50) ? i : 50;
            int p = i * 50 + kk;
            val = (kk < vc) ? sum_parts(sacc_part, p, b2, bscore) : NEGV;
            cidx[c] = bjj[p];
        } else val = -3.4e38f;
        float m = val;
#pragma unroll
        for (int d = 1; d < 64; d <<= 1) m = fmaxf(m, __shfl_xor(m, d));
        float e = (c < 51) ? __expf(val - m) : 0.f;
        float s = e;
#pragma unroll
        for (int d = 1; d < 64; d <<= 1) s += __shfl_xor(s, d);
        pw[tid] = e / s;
    }
    __syncthreads();
    {
        int d = tid * 2;   // 256 threads x 2 dims = 512
        float a0 = 0.f, a1 = 0.f, f0 = 0.f, f1 = 0.f;
        for (int c = 0; c < 51; c++) {
            int ci = cidx[c];
            float pc = pw[c];
            int gv = *(const int*)(g_bf + (size_t)ci * 512 + d);
            int hv = *(const int*)(G2bf + (size_t)ci * 512 + d);
            a0 += pc * bf2f((short)(gv & 0xffff));
            a1 += pc * bf2f((short)((uint32_t)gv >> 16));
            f0 += pc * bf2f((short)(hv & 0xffff));
            f1 += pc * bf2f((short)((uint32_t)hv >> 16));
        }
        int g1v = *(const int*)(G1bf + (size_t)i * 512 + d);
        f0 += bf2f((short)(g1v & 0xffff)) + bfv[d];
        f1 += bf2f((short)((uint32_t)g1v >> 16)) + bfv[d + 1];
        float fg0 = 1.f / (1.f + __expf(-f0));
        float fg1 = 1.f / (1.f + __expf(-f1));
        int gov = *(const int*)(g_bf + (size_t)i * 512 + d);
        float o0 = fg0 * bf2f((short)(gov & 0xffff)) + (1.f - fg0) * a0;
        float o1 = fg1 * bf2f((short)((uint32_t)gov >> 16)) + (1.f - fg1) * a1;
        uint32_t pack = ((uint32_t)(uint16_t)f2bf(o0)) | (((uint32_t)(uint16_t)f2bf(o1)) << 16);
        *(int*)(gnew + (size_t)i * 512 + d) = (int)pack;
    }
}

__global__ void finalize_kernel(const float* __restrict__ sacc_part, const float* __restrict__ b2,
                                const float* __restrict__ bscore, float* __restrict__ out) {
    int idx = blockIdx.x * 256 + threadIdx.x;
    if (idx >= 1024 * 51) return;
    int i = idx / 51, c = idx % 51;
    float v;
    if (i == 0) v = (c <= 1) ? 0.f : NEGV;
    else if (c == 0) v = 0.f;
    else {
        int kk = c - 1;
        int vc = (i < 50) ? i : 50;
        int p = i * 50 + kk;
        v = (kk < vc) ? sum_parts(sacc_part, p, b2, bscore) : NEGV;
    }
    out[idx] = v;
}

// ---------------------------------------------------------------------------
// Workspace. ant separate (topk reads ant while writing P).
// ---------------------------------------------------------------------------
static constexpr size_t OFF_W1T    = 0;          // 3,145,728
static constexpr size_t OFF_WFT    = 3145728;    // 1,048,576
static constexpr size_t OFF_CWBF   = 4194304;    // 524,288
static constexpr size_t OFF_W1C8   = 4718592;    // 524,288 (fp8)
static constexpr size_t OFF_W2P    = 5242880;    // 4096
static constexpr size_t OFF_B1P    = 5246976;    // 4096
static constexpr size_t OFF_CG     = 5251072;    // 32,768
static constexpr size_t OFF_FTABBF = 5283840;    // 36,864
static constexpr size_t OFF_GBF    = 5320704;    // 1,048,576
static constexpr size_t OFF_TMPBF  = 6369280;    // 1,048,576
static constexpr size_t OFF_BSC    = 7417856;    // 204,800
static constexpr size_t OFF_BJ     = 7622656;    // 204,800
static constexpr size_t OFF_FC     = 7827456;    // 204,800
static constexpr size_t OFF_AB0    = 8032256;    // 4,194,304
static constexpr size_t OFF_SACCP  = 12226560;   // 8*51200*4 = 1,638,400
static constexpr size_t OFF_P      = 13864960;   // 26,214,400 (fp8)
static constexpr size_t OFF_ANT    = 40079360;   // 4,194,304
static constexpr size_t OFF_G1BF   = 44273664;   // 1,048,576
static constexpr size_t OFF_G2BF   = 45322240;   // 1,048,576
static constexpr size_t OFF_GNEW   = 46370816;   // 1,048,576

extern "C" void kernel_launch(void* const* d_in, const int* in_sizes, int n_in,
                              void* d_out, int out_size, void* d_ws, size_t ws_size,
                              hipStream_t stream) {
    const float* g_i   = (const float*)d_in[0];
    const float* ms    = (const float*)d_in[1];
    const float* diste = (const float*)d_in[2];
    const float* gene  = (const float*)d_in[3];
    const float* spke  = (const float*)d_in[4];
    const float* cW    = (const float*)d_in[5];
    const float* W1    = (const float*)d_in[6];
    const float* b1    = (const float*)d_in[7];
    const float* W2    = (const float*)d_in[8];
    const float* b2    = (const float*)d_in[9];
    const float* Wf    = (const float*)d_in[10];
    const float* bfv   = (const float*)d_in[11];
    const int* sidx    = (const int*)d_in[12];
    const int* eidx    = (const int*)d_in[13];
    const int* gid     = (const int*)d_in[14];
    const int* spk     = (const int*)d_in[15];
    float* out = (float*)d_out;

    char* ws = (char*)d_ws;
    short* W1T     = (short*)(ws + OFF_W1T);
    short* WfT     = (short*)(ws + OFF_WFT);
    short* cwbf    = (short*)(ws + OFF_CWBF);
    uint8_t* W1c8  = (uint8_t*)(ws + OFF_W1C8);
    float* w2p     = (float*)(ws + OFF_W2P);
    float* b1p     = (float*)(ws + OFF_B1P);
    float* Cg      = (float*)(ws + OFF_CG);
    short* Ftabbf  = (short*)(ws + OFF_FTABBF);
    short* g_bf    = (short*)(ws + OFF_GBF);
    short* tmpbf   = (short*)(ws + OFF_TMPBF);
    float* ant     = (float*)(ws + OFF_ANT);
    float* bsc     = (float*)(ws + OFF_BSC);
    int*   bjj     = (int*)(ws + OFF_BJ);
    int*   fcode   = (int*)(ws + OFF_FC);
    short* AB0bf   = (short*)(ws + OFF_AB0);
    float* saccp   = (float*)(ws + OFF_SACCP);
    short* G1bf    = (short*)(ws + OFF_G1BF);
    short* G2bf    = (short*)(ws + OFF_G2BF);
    short* gnew    = (short*)(ws + OFF_GNEW);
    uint8_t* P     = (uint8_t*)(ws + OFF_P);

    // 1. prep
    prep_all_kernel<<<3824, 256, 0, stream>>>(W1, Wf, cW, W2, b1, gene, diste, spke, g_i,
                                              W1T, WfT, W1c8, cwbf, w2p, b1p, Cg, Ftabbf, g_bf);
    // 2. AB0(t=0) + coarse1 + G1 + G2 (merged, all independent)
    ab0_coarse1_kernel<<<224, 256, 0, stream>>>(g_bf, W1T, AB0bf, cwbf, tmpbf,
                                                WfT, G1bf, G2bf, gid, Cg, b1p);
    // 3. coarse2: ant = tmp @ g^T
    gemm_bt<0><<<dim3(8, 8, 1), 256, 0, stream>>>(
        tmpbf, 512, g_bf, 512, ant, 1024, 512, 0, 0, nullptr, nullptr, nullptr);
    // 4. exact top-50 + features + P(t=0) fill
    topk_kernel<<<1024, 256, 0, stream>>>(ant, ms, sidx, eidx, spk, g_bf, bsc, bjj, fcode, P);
    // 5. fused score t=0
    fused_score_kernel<<<dim3(8, 400), 256, 0, stream>>>(
        P, W1c8, bjj, fcode, AB0bf, Ftabbf, w2p, saccp);
    // 6. softmax + gate update (gate GEMM algebraically folded via G1/G2)
    softmax_gate_kernel<<<1024, 256, 0, stream>>>(saccp, b2, bsc, bjj, g_bf,
                                                  G1bf, G2bf, bfv, gnew);
    // 7. AB0(t=1) from gnew + pairprod(t=1) (merged, independent)
    ab0_pairprod_kernel<<<3328, 256, 0, stream>>>(gnew, W1T, AB0bf, gid, Cg, b1p, bjj, P);
    // 8. fused score t=1
    fused_score_kernel<<<dim3(8, 400), 256, 0, stream>>>(
        P, W1c8, bjj, fcode, AB0bf, Ftabbf, w2p, saccp);
    // 9. finalize
    finalize_kernel<<<204, 256, 0, stream>>>(saccp, b2, bsc, out);
}

// Round 14
// 365.558 us; speedup vs baseline: 1.0733x; 1.0733x over previous
//
#include <hip/hip_runtime.h>
#include <cstdint>
#include <cstddef>

#define NEGV (-1e10f)

typedef short short8 __attribute__((ext_vector_type(8)));
typedef short short4_t __attribute__((ext_vector_type(4)));
typedef float f32x4 __attribute__((ext_vector_type(4)));

__device__ __forceinline__ float bf2f(short s) {
    union { float f; uint32_t u; } x;
    x.u = ((uint32_t)(uint16_t)s) << 16;
    return x.f;
}
__device__ __forceinline__ short f2bf(float f) {
    union { float f; uint32_t u; } x;
    x.f = f;
    uint32_t u = x.u;
    uint32_t r = (u + 0x7fffu + ((u >> 16) & 1u)) >> 16;
    return (short)r;
}

__device__ __forceinline__ void gl2lds16(const void* gsrc, void* ldst) {
    __builtin_amdgcn_global_load_lds(
        (const __attribute__((address_space(1))) void*)gsrc,
        (__attribute__((address_space(3))) void*)ldst, 16, 0, 0);
}

// pack 8 f32 -> 8 fp8(e4m3) bytes via HW cvt_pk
__device__ __forceinline__ void pack8_fp8(const float* pr, int* w0, int* w1) {
    int a = __builtin_amdgcn_cvt_pk_fp8_f32(pr[0], pr[1], 0, false);
    a = __builtin_amdgcn_cvt_pk_fp8_f32(pr[2], pr[3], a, true);
    int b = __builtin_amdgcn_cvt_pk_fp8_f32(pr[4], pr[5], 0, false);
    b = __builtin_amdgcn_cvt_pk_fp8_f32(pr[6], pr[7], b, true);
    *w0 = a; *w1 = b;
}

// ---------------------------------------------------------------------------
// bf16 GEMM core: C[M,N] = A[M,K] * BT[N,K]^T. 128x128 tile, BK=64, 4 waves,
// mfma_f32_16x16x32_bf16, XOR-rotated LDS granules (conflict-free, r3).
// epi: 0 = store f32, 1 = store bf16,
//      4 = store bf16 + bias (Cg[gid]+b1p) when z==0   (AB0 build)
// ---------------------------------------------------------------------------
__device__ __forceinline__ void gemm_core(
    int epi, const short* __restrict__ A, int lda,
    const short* __restrict__ BT, int ldb,
    void* __restrict__ Cout, int ldc, int K,
    int bn, int bm, int z, int zBT, int zC,
    const int* __restrict__ gid, const float* __restrict__ Cg,
    const float* __restrict__ b1p)
{
    __shared__ short As[128 * 64];
    __shared__ short Bs[128 * 64];

    const int tid = threadIdx.x;
    const int lane = tid & 63;
    const int w = tid >> 6;
    const int quad = lane >> 4;
    const int l15 = lane & 15;
    const int colz = z * zC;
    BT += (size_t)z * zBT;

    f32x4 acc[4][4];
#pragma unroll
    for (int mi = 0; mi < 4; mi++)
#pragma unroll
        for (int ni = 0; ni < 4; ni++)
            acc[mi][ni] = {0.f, 0.f, 0.f, 0.f};

    const int mb = (w >> 1) * 64, nb = (w & 1) * 64;
    const int r8 = lane >> 3;
    const int sg = ((lane & 7) - r8) & 7;

    for (int k0 = 0; k0 < K; k0 += 64) {
#pragma unroll
        for (int c = 0; c < 4; c++) {
            int chunk = w * 4 + c;
            int row = chunk * 8 + r8;
            gl2lds16(BT + (size_t)(bn * 128 + row) * ldb + k0 + sg * 8, Bs + chunk * 512);
            gl2lds16(A + (size_t)(bm * 128 + row) * lda + k0 + sg * 8, As + chunk * 512);
        }
        __syncthreads();
#pragma unroll
        for (int ks = 0; ks < 64; ks += 32) {
            short8 af[4], bfr[4];
            const int gb = quad + (ks >> 3);
#pragma unroll
            for (int mi = 0; mi < 4; mi++) {
                int row = mb + mi * 16 + l15;
                af[mi] = *(const short8*)(As + row * 64 + (((gb + row) & 7) << 3));
            }
#pragma unroll
            for (int ni = 0; ni < 4; ni++) {
                int row = nb + ni * 16 + l15;
                bfr[ni] = *(const short8*)(Bs + row * 64 + (((gb + row) & 7) << 3));
            }
#pragma unroll
            for (int mi = 0; mi < 4; mi++)
#pragma unroll
                for (int ni = 0; ni < 4; ni++)
                    acc[mi][ni] = __builtin_amdgcn_mfma_f32_16x16x32_bf16(
                        af[mi], bfr[ni], acc[mi][ni], 0, 0, 0);
        }
        __syncthreads();
    }

#pragma unroll
    for (int mi = 0; mi < 4; mi++)
#pragma unroll
        for (int ni = 0; ni < 4; ni++) {
            int col = bn * 128 + nb + ni * 16 + l15;
#pragma unroll
            for (int reg = 0; reg < 4; reg++) {
                int rowg = bm * 128 + mb + mi * 16 + quad * 4 + reg;
                float v = acc[mi][ni][reg];
                if (epi == 0) {
                    ((float*)Cout)[(size_t)rowg * ldc + col] = v;
                } else if (epi == 1) {
                    ((short*)Cout)[(size_t)rowg * ldc + col] = f2bf(v);
                } else {  // epi == 4
                    if (z == 0)
                        v += Cg[gid[rowg] * 1024 + col] + b1p[col];
                    ((short*)Cout)[(size_t)rowg * ldc + colz + col] = f2bf(v);
                }
            }
        }
}

template <int EPI>
__global__ __launch_bounds__(256) void gemm_bt(
    const short* __restrict__ A, int lda,
    const short* __restrict__ BT, int ldb,
    void* __restrict__ Cout, int ldc, int K,
    int zBT, int zC,
    const int* __restrict__ gid, const float* __restrict__ Cg,
    const float* __restrict__ b1p)
{
    gemm_core(EPI, A, lda, BT, ldb, Cout, ldc, K,
              blockIdx.x, blockIdx.y, blockIdx.z, zBT, zC, gid, Cg, b1p);
}

// pairprod body: 4 granules/thread, contiguous 8B stores
__device__ __forceinline__ void pairprod_body(
    int pb, int tid, const short* __restrict__ g_bf,
    const int* __restrict__ bjj, uint8_t* __restrict__ P)
{
#pragma unroll
    for (int it = 0; it < 4; it++) {
        int gidx = pb * 1024 + it * 256 + tid;
        if (gidx >= 51200 * 64) return;
        int p = gidx >> 6, g8 = gidx & 63;
        int i = p / 50;
        int j = bjj[p];
        short8 va = *(const short8*)(g_bf + (size_t)i * 512 + g8 * 8);
        short8 vb = *(const short8*)(g_bf + (size_t)j * 512 + g8 * 8);
        float pr[8];
#pragma unroll
        for (int e = 0; e < 8; e++) pr[e] = bf2f(va[e]) * bf2f(vb[e]);
        int2 out;
        pack8_fp8(pr, &out.x, &out.y);
        *(int2*)(P + (size_t)p * 512 + g8 * 8) = out;
    }
}

// Combined (all independent, all read g_bf):
//   [0,128)   AB0 GEMM (epi4, 2 z-halves)
//   [128,160) coarse1: tmp = g @ cW^T        (epi1)
//   [160,192) G1 = g @ Wf_top^T              (epi1)
//   [192,224) G2 = g @ Wf_bot^T              (epi1)
__global__ __launch_bounds__(256) void ab0_coarse1_kernel(
    const short* __restrict__ g_bf, const short* __restrict__ W1T,
    short* __restrict__ AB0bf, const short* __restrict__ cwbf,
    short* __restrict__ tmpbf, const short* __restrict__ WfT,
    short* __restrict__ G1bf, short* __restrict__ G2bf,
    const int* __restrict__ gid, const float* __restrict__ Cg,
    const float* __restrict__ b1p)
{
    int bx = blockIdx.x;
    if (bx < 128) {
        int z = bx >> 6, rem = bx & 63;
        gemm_core(4, g_bf, 512, W1T, 1536, AB0bf, 2048, 512,
                  rem & 7, rem >> 3, z, 512, 1024, gid, Cg, b1p);
    } else if (bx < 160) {
        int r = bx - 128;
        gemm_core(1, g_bf, 512, cwbf, 512, tmpbf, 512, 512,
                  r & 3, r >> 2, 0, 0, 0, nullptr, nullptr, nullptr);
    } else if (bx < 192) {
        int r = bx - 160;
        gemm_core(1, g_bf, 512, WfT, 1024, G1bf, 512, 512,
                  r & 3, r >> 2, 0, 0, 0, nullptr, nullptr, nullptr);
    } else {
        int r = bx - 192;
        gemm_core(1, g_bf, 512, WfT + 512, 1024, G2bf, 512, 512,
                  r & 3, r >> 2, 0, 0, 0, nullptr, nullptr, nullptr);
    }
}

// Combined: blocks [0,128) AB0 GEMM (epi4) from gnew, [128,3328) pairprod(gnew)
__global__ __launch_bounds__(256) void ab0_pairprod_kernel(
    const short* __restrict__ gnew, const short* __restrict__ W1T,
    short* __restrict__ AB0bf,
    const int* __restrict__ gid, const float* __restrict__ Cg,
    const float* __restrict__ b1p,
    const int* __restrict__ bjj, uint8_t* __restrict__ P)
{
    int bx = blockIdx.x;
    if (bx < 128) {
        int z = bx >> 6, rem = bx & 63;
        gemm_core(4, gnew, 512, W1T, 1536, AB0bf, 2048, 512,
                  rem & 7, rem >> 3, z, 512, 1024, gid, Cg, b1p);
    } else {
        pairprod_body(bx - 128, threadIdx.x, gnew, bjj, P);
    }
}

// ---------------------------------------------------------------------------
// Fused score GEMM, fp8 e4m3 (r6/r8/r10/r11-verified 81.5 µs): 128 pairs x
// 128 hidden, K=512, BK=128. Grid (bn=8, bm=400): temporal co-scheduling
// shares P via L3; XCD x only sees bn==x -> W1c8 slab L2-resident. Comb bias
// staged to LDS; no global atomics.
// DO NOT TOUCH THIS KERNEL:
//   r7  (K-permuted layouts)      -> +47 MB WRITE, slower
//   r9  (128x256 tile)            -> acc spill, 2.4x slower
//   r12 (b128 fragment reads)     -> +4 live VGPR -> spill, 92 µs
// V60+A64 = 124/128 of the 4-wave budget — register-saturated by design.
// ---------------------------------------------------------------------------
__global__ __launch_bounds__(256, 4) void fused_score_kernel(
    const uint8_t* __restrict__ P,      // [51200][512] fp8
    const uint8_t* __restrict__ W1c8,   // [1024][512] fp8 (x16)
    const int* __restrict__ bjj,
    const int* __restrict__ fcode,
    const short* __restrict__ AB0bf,    // [1024][2048] bf16: A0 | B0
    const short* __restrict__ Ftabbf,   // [18][1024] bf16
    const float* __restrict__ w2p,      // [1024]
    float* __restrict__ sacc_part)      // [8][51200]
{
    __shared__ short U[16896];          // As(16K)|Bs(16K) bytes; reused comb[128][132]
    __shared__ int iL[128], jL[128], fcL[128];
    __shared__ float saccs[128];

    uint8_t* As = (uint8_t*)U;
    uint8_t* Bs = As + 16384;

    const int tid = threadIdx.x, lane = tid & 63, w = tid >> 6;
    const int quad = lane >> 4, l15 = lane & 15;
    const int bn = blockIdx.x, bm = blockIdx.y;
    const int mb = (w >> 1) * 64, nb = (w & 1) * 64;
    const int nbase = bn * 128;

    if (tid < 128) {
        int p = bm * 128 + tid;
        iL[tid] = p / 50;
        jL[tid] = bjj[p];
        fcL[tid] = fcode[p];
        saccs[tid] = 0.f;
    }
    __syncthreads();

    f32x4 acc[4][4];
#pragma unroll
    for (int mi = 0; mi < 4; mi++)
#pragma unroll
        for (int ni = 0; ni < 4; ni++)
            acc[mi][ni] = {0.f, 0.f, 0.f, 0.f};

    const int r8 = lane >> 3;
    const int sg = ((lane & 7) - r8) & 7;   // rotated 16B source granule

    for (int k0 = 0; k0 < 512; k0 += 128) {
#pragma unroll
        for (int c = 0; c < 4; c++) {
            int chunk = w * 4 + c;
            int row = chunk * 8 + r8;
            gl2lds16(W1c8 + (size_t)(nbase + row) * 512 + k0 + sg * 16, Bs + chunk * 1024);
            gl2lds16(P + (size_t)(bm * 128 + row) * 512 + k0 + sg * 16, As + chunk * 1024);
        }
        __syncthreads();
#pragma unroll
        for (int s = 0; s < 4; s++) {
            long a[4], b[4];
            const int g16 = s * 2 + (quad >> 1);
            const int off8 = (quad & 1) * 8;
#pragma unroll
            for (int mi = 0; mi < 4; mi++) {
                int row = mb + mi * 16 + l15;
                a[mi] = *(const long*)(As + row * 128 + (((g16 + row) & 7) << 4) + off8);
            }
#pragma unroll
            for (int ni = 0; ni < 4; ni++) {
                int row = nb + ni * 16 + l15;
                b[ni] = *(const long*)(Bs + row * 128 + (((g16 + row) & 7) << 4) + off8);
            }
#pragma unroll
            for (int mi = 0; mi < 4; mi++)
#pragma unroll
                for (int ni = 0; ni < 4; ni++)
                    acc[mi][ni] = __builtin_amdgcn_mfma_f32_16x16x32_fp8_fp8(
                        a[mi], b[ni], acc[mi][ni], 0, 0, 0);
        }
        __syncthreads();
    }

    // ---- stage combined bias comb[r][c] (bf16, stride 132) into U ----
    {
        int r = tid >> 1;
        int colb = (tid & 1) * 64;
        int i = iL[r], j = jL[r], fc = fcL[r];
        const short* pa = AB0bf + (size_t)i * 2048 + nbase + colb;
        const short* pb = AB0bf + (size_t)j * 2048 + 1024 + nbase + colb;
        const short* pf = Ftabbf + fc * 1024 + nbase + colb;
        short* dst = U + r * 132 + colb;
#pragma unroll
        for (int c8 = 0; c8 < 8; c8++) {
            short8 va = *(const short8*)(pa + c8 * 8);
            short8 vb = *(const short8*)(pb + c8 * 8);
            short8 vf = *(const short8*)(pf + c8 * 8);
            short4_t lo, hi;
#pragma unroll
            for (int e = 0; e < 4; e++)
                lo[e] = f2bf(bf2f(va[e]) + bf2f(vb[e]) + bf2f(vf[e]));
#pragma unroll
            for (int e = 0; e < 4; e++)
                hi[e] = f2bf(bf2f(va[e + 4]) + bf2f(vb[e + 4]) + bf2f(vf[e + 4]));
            *(short4_t*)(dst + c8 * 8) = lo;
            *(short4_t*)(dst + c8 * 8 + 4) = hi;
        }
    }
    __syncthreads();

    // ---- layer-2 epilogue: pure LDS ----
    float w2v[4];
#pragma unroll
    for (int ni = 0; ni < 4; ni++) w2v[ni] = w2p[nbase + nb + ni * 16 + l15];
#pragma unroll
    for (int mi = 0; mi < 4; mi++)
#pragma unroll
        for (int reg = 0; reg < 4; reg++) {
            int rloc = mb + mi * 16 + quad * 4 + reg;
            float s = 0.f;
#pragma unroll
            for (int ni = 0; ni < 4; ni++) {
                float pre = acc[mi][ni][reg] * 0.0625f + bf2f(U[rloc * 132 + nb + ni * 16 + l15]);
                s += fmaxf(pre, 0.f) * w2v[ni];
            }
#pragma unroll
            for (int m = 1; m < 16; m <<= 1) s += __shfl_xor(s, m);
            if (l15 == 0) atomicAdd(&saccs[rloc], s);
        }
    __syncthreads();
    if (tid < 128)
        sacc_part[(size_t)bn * 51200 + bm * 128 + tid] = saccs[tid];
}

// ---------------------------------------------------------------------------
// Unified prep.
// ---------------------------------------------------------------------------
__device__ __forceinline__ void transpose_tile(
    const float* __restrict__ src, short* __restrict__ dst,
    int ncolsPhys, int dstStride, int bx, int by, int t) {
    __shared__ float tile[64][65];
    const int kin0 = bx * 64, hh0 = by * 64;
#pragma unroll
    for (int r = 0; r < 16; r++) {
        int kin_l = r * 4 + (t >> 6);
        int hh_l = t & 63;
        int hh = hh0 + hh_l;
        float v = (hh < ncolsPhys) ? src[(size_t)(kin0 + kin_l) * ncolsPhys + hh] : 0.f;
        tile[kin_l][hh_l] = v;
    }
    __syncthreads();
#pragma unroll
    for (int r = 0; r < 16; r++) {
        int hh_l = r * 4 + (t >> 6);
        int kin_l = t & 63;
        dst[(size_t)(hh0 + hh_l) * dstStride + kin0 + kin_l] = f2bf(tile[kin_l][hh_l]);
    }
}

// W1c slice (kin in [1024,1536)) -> fp8 x16, dst[hh][kin-1024], ld 512
__device__ __forceinline__ void transpose_tile_fp8(
    const float* __restrict__ W1, uint8_t* __restrict__ dst,
    int bx, int by, int t) {
    __shared__ float tile8[64][65];
    const int kin0 = 1024 + bx * 64, hh0 = by * 64;
#pragma unroll
    for (int r = 0; r < 16; r++) {
        int kin_l = r * 4 + (t >> 6);
        int hh_l = t & 63;
        int hh = hh0 + hh_l;
        float v = (hh < 1000) ? W1[(size_t)(kin0 + kin_l) * 1000 + hh] : 0.f;
        tile8[kin_l][hh_l] = v;
    }
    __syncthreads();
#pragma unroll
    for (int r = 0; r < 16; r++) {
        int hh_l = r * 4 + (t >> 6);
        int kin_l = t & 63;
        float v = tile8[kin_l][hh_l] * 16.f;
        int pk = __builtin_amdgcn_cvt_pk_fp8_f32(v, 0.f, 0, false);
        dst[(size_t)(hh0 + hh_l) * 512 + bx * 64 + kin_l] = (uint8_t)(pk & 0xff);
    }
}

__global__ __launch_bounds__(256) void prep_all_kernel(
    const float* __restrict__ W1, const float* __restrict__ Wf,
    const float* __restrict__ cW, const float* __restrict__ W2,
    const float* __restrict__ b1, const float* __restrict__ genre_e,
    const float* __restrict__ dist_e, const float* __restrict__ spk_e,
    const float* __restrict__ g,
    short* W1T, short* WfT, uint8_t* W1c8, short* cwbf, float* w2p, float* b1p,
    float* Cg, short* Ftabbf, short* g_bf) {
    int b = blockIdx.x;
    int t = threadIdx.x;
    if (b < 384) { transpose_tile(W1, W1T, 1000, 1536, b % 24, b / 24, t); return; }
    if (b < 512) { int bb = b - 384; transpose_tile(Wf, WfT, 512, 1024, bb % 16, bb / 16, t); return; }
    if (b < 640) { int bb = b - 512; transpose_tile_fp8(W1, W1c8, bb % 8, bb / 8, t); return; }
    int idx = (b - 640) * 256 + t;
    if (idx < 512 * 512) { cwbf[idx] = f2bf(cW[idx]); return; }
    idx -= 512 * 512;
    if (idx < 1024) { w2p[idx] = (idx < 1000) ? W2[idx] : 0.f; return; }
    idx -= 1024;
    if (idx < 1024) { b1p[idx] = (idx < 1000) ? b1[idx] : 0.f; return; }
    idx -= 1024;
    if (idx < 8 * 1024) {
        int gg = idx >> 10, h = idx & 1023;
        float v = 0.f;
        if (h < 1000)
            for (int e = 0; e < 20; e++) v += genre_e[gg * 20 + e] * W1[(size_t)(1556 + e) * 1000 + h];
        Cg[idx] = v;
        return;
    }
    idx -= 8 * 1024;
    if (idx < 18 * 1024) {
        int code = idx >> 10, h = idx & 1023;
        int bb = code >> 1, s2 = code & 1;
        float v = 0.f;
        if (h < 1000) {
            for (int e = 0; e < 20; e++) v += dist_e[bb * 20 + e] * W1[(size_t)(1536 + e) * 1000 + h];
            for (int e = 0; e < 20; e++) v += spk_e[(s2 + 1) * 20 + e] * W1[(size_t)(1576 + e) * 1000 + h];
        }
        Ftabbf[idx] = f2bf(v);
        return;
    }
    idx -= 18 * 1024;
    if (idx < 1024 * 512) g_bf[idx] = f2bf(g[idx]);
}

// ---------------------------------------------------------------------------
// Exact top-50 per row + fused P fill (fp8, contiguous). Candidate mapping
// j = c*64 + lane -> coalesced ant reads. Wave 0 selects; all 4 waves fill.
// ---------------------------------------------------------------------------
__global__ __launch_bounds__(256) void topk_kernel(
    const float* __restrict__ ant, const float* __restrict__ ms,
    const int* __restrict__ sidx, const int* __restrict__ eidx,
    const int* __restrict__ spk, const short* __restrict__ g_bf,
    float* __restrict__ bscore, int* __restrict__ bjj, int* __restrict__ fcodes,
    uint8_t* __restrict__ P) {
    int i = blockIdx.x;
    int tid = threadIdx.x;
    __shared__ int bjL[50];
    if (tid < 64) {
        int lane = tid;
        float v[16];
        float si = ms[i];
#pragma unroll
        for (int c = 0; c < 16; c++) {
            int j = c * 64 + lane;
            float val = ant[(size_t)i * 1024 + j] + si + ms[j];
            v[c] = (j < i) ? val : (val + NEGV);
        }
        int ei = eidx[i];
        int spi = spk[i];
        for (int r = 0; r < 50; r++) {
            float bv = -3.4e38f;
            int bj = 1 << 30;
#pragma unroll
            for (int c = 0; c < 16; c++) {
                int j = c * 64 + lane;
                if (v[c] > bv) { bv = v[c]; bj = j; }
            }
#pragma unroll
            for (int m = 1; m < 64; m <<= 1) {
                float ov = __shfl_xor(bv, m);
                int oj = __shfl_xor(bj, m);
                if (ov > bv || (ov == bv && oj < bj)) { bv = ov; bj = oj; }
            }
            if (lane == 0) {
                bscore[i * 50 + r] = bv;
                bjj[i * 50 + r] = bj;
                bjL[r] = bj;
                int d = ei - sidx[bj];
                int bin = (d > 1) + (d > 2) + (d > 3) + (d > 4) + (d > 8) + (d > 16) + (d > 32) + (d > 64);
                int lab = (spi == spk[bj]) ? 0 : 1;
                fcodes[i * 50 + r] = bin * 2 + lab;
            }
#pragma unroll
            for (int c = 0; c < 16; c++)
                if (bj == c * 64 + lane) v[c] = -3.4e38f;
        }
    }
    __syncthreads();
    int g8 = tid & 63;
    short8 va = *(const short8*)(g_bf + (size_t)i * 512 + g8 * 8);
    for (int r = tid >> 6; r < 50; r += 4) {
        int j = bjL[r];
        short8 vb = *(const short8*)(g_bf + (size_t)j * 512 + g8 * 8);
        float pr[8];
#pragma unroll
        for (int e = 0; e < 8; e++) pr[e] = bf2f(va[e]) * bf2f(vb[e]);
        int2 out;
        pack8_fp8(pr, &out.x, &out.y);
        *(int2*)(P + (size_t)(i * 50 + r) * 512 + g8 * 8) = out;
    }
}

__device__ __forceinline__ float sum_parts(const float* __restrict__ sacc_part, int p,
                                           const float* __restrict__ b2,
                                           const float* __restrict__ bscore) {
    float s = b2[0] + bscore[p];
#pragma unroll
    for (int q = 0; q < 8; q++) s += sacc_part[(size_t)q * 51200 + p];
    return s;
}

// ---------------------------------------------------------------------------
// Softmax + full gate update in one kernel (gate GEMM eliminated, r11):
//   f_pre[i] = G1[i] + sum_c p_c * G2[cidx_c] + bf
//   gnew[i]  = f*g[i] + (1-f)*a_n,  a_n = sum_c p_c * g[cidx_c]
// Each thread handles 2 consecutive dims via dword gathers (r12).
// ---------------------------------------------------------------------------
__global__ __launch_bounds__(256) void softmax_gate_kernel(
    const float* __restrict__ sacc_part, const float* __restrict__ b2,
    const float* __restrict__ bscore,
    const int* __restrict__ bjj, const short* __restrict__ g_bf,
    const short* __restrict__ G1bf, const short* __restrict__ G2bf,
    const float* __restrict__ bfv, short* __restrict__ gnew) {
    int i = blockIdx.x;
    int tid = threadIdx.x;
    if (i == 0) {  // span 0 never refined
        ((int*)gnew)[tid] = ((const int*)g_bf)[tid];
        return;
    }
    __shared__ float pw[64];
    __shared__ int cidx[51];
    if (tid < 64) {
        int c = tid;
        float val;
        if (c == 0) { val = 0.f; cidx[0] = i; }
        else if (c < 51) {
            int kk = c - 1;
            int vc = (i < 50) ? i : 50;
            int p = i * 50 + kk;
            val = (kk < vc) ? sum_parts(sacc_part, p, b2, bscore) : NEGV;
            cidx[c] = bjj[p];
        } else val = -3.4e38f;
        float m = val;
#pragma unroll
        for (int d = 1; d < 64; d <<= 1) m = fmaxf(m, __shfl_xor(m, d));
        float e = (c < 51) ? __expf(val - m) : 0.f;
        float s = e;
#pragma unroll
        for (int d = 1; d < 64; d <<= 1) s += __shfl_xor(s, d);
        pw[tid] = e / s;
    }
    __syncthreads();
    {
        int d = tid * 2;   // 256 threads x 2 dims = 512
        float a0 = 0.f, a1 = 0.f, f0 = 0.f, f1 = 0.f;
        for (int c = 0; c < 51; c++) {
            int ci = cidx[c];
            float pc = pw[c];
            int gv = *(const int*)(g_bf + (size_t)ci * 512 + d);
            int hv = *(const int*)(G2bf + (size_t)ci * 512 + d);
            a0 += pc * bf2f((short)(gv & 0xffff));
            a1 += pc * bf2f((short)((uint32_t)gv >> 16));
            f0 += pc * bf2f((short)(hv & 0xffff));
            f1 += pc * bf2f((short)((uint32_t)hv >> 16));
        }
        int g1v = *(const int*)(G1bf + (size_t)i * 512 + d);
        f0 += bf2f((short)(g1v & 0xffff)) + bfv[d];
        f1 += bf2f((short)((uint32_t)g1v >> 16)) + bfv[d + 1];
        float fg0 = 1.f / (1.f + __expf(-f0));
        float fg1 = 1.f / (1.f + __expf(-f1));
        int gov = *(const int*)(g_bf + (size_t)i * 512 + d);
        float o0 = fg0 * bf2f((short)(gov & 0xffff)) + (1.f - fg0) * a0;
        float o1 = fg1 * bf2f((short)((uint32_t)gov >> 16)) + (1.f - fg1) * a1;
        uint32_t pack = ((uint32_t)(uint16_t)f2bf(o0)) | (((uint32_t)(uint16_t)f2bf(o1)) << 16);
        *(int*)(gnew + (size_t)i * 512 + d) = (int)pack;
    }
}

__global__ void finalize_kernel(const float* __restrict__ sacc_part, const float* __restrict__ b2,
                                const float* __restrict__ bscore, float* __restrict__ out) {
    int idx = blockIdx.x * 256 + threadIdx.x;
    if (idx >= 1024 * 51) return;
    int i = idx / 51, c = idx % 51;
    float v;
    if (i == 0) v = (c <= 1) ? 0.f : NEGV;
    else if (c == 0) v = 0.f;
    else {
        int kk = c - 1;
        int vc = (i < 50) ? i : 50;
        int p = i * 50 + kk;
        v = (kk < vc) ? sum_parts(sacc_part, p, b2, bscore) : NEGV;
    }
    out[idx] = v;
}

// ---------------------------------------------------------------------------
// Workspace. ant separate (topk reads ant while writing P).
// ---------------------------------------------------------------------------
static constexpr size_t OFF_W1T    = 0;          // 3,145,728
static constexpr size_t OFF_WFT    = 3145728;    // 1,048,576
static constexpr size_t OFF_CWBF   = 4194304;    // 524,288
static constexpr size_t OFF_W1C8   = 4718592;    // 524,288 (fp8)
static constexpr size_t OFF_W2P    = 5242880;    // 4096
static constexpr size_t OFF_B1P    = 5246976;    // 4096
static constexpr size_t OFF_CG     = 5251072;    // 32,768
static constexpr size_t OFF_FTABBF = 5283840;    // 36,864
static constexpr size_t OFF_GBF    = 5320704;    // 1,048,576
static constexpr size_t OFF_TMPBF  = 6369280;    // 1,048,576
static constexpr size_t OFF_BSC    = 7417856;    // 204,800
static constexpr size_t OFF_BJ     = 7622656;    // 204,800
static constexpr size_t OFF_FC     = 7827456;    // 204,800
static constexpr size_t OFF_AB0    = 8032256;    // 4,194,304
static constexpr size_t OFF_SACCP  = 12226560;   // 8*51200*4 = 1,638,400
static constexpr size_t OFF_P      = 13864960;   // 26,214,400 (fp8)
static constexpr size_t OFF_ANT    = 40079360;   // 4,194,304
static constexpr size_t OFF_G1BF   = 44273664;   // 1,048,576
static constexpr size_t OFF_G2BF   = 45322240;   // 1,048,576
static constexpr size_t OFF_GNEW   = 46370816;   // 1,048,576

extern "C" void kernel_launch(void* const* d_in, const int* in_sizes, int n_in,
                              void* d_out, int out_size, void* d_ws, size_t ws_size,
                              hipStream_t stream) {
    const float* g_i   = (const float*)d_in[0];
    const float* ms    = (const float*)d_in[1];
    const float* diste = (const float*)d_in[2];
    const float* gene  = (const float*)d_in[3];
    const float* spke  = (const float*)d_in[4];
    const float* cW    = (const float*)d_in[5];
    const float* W1    = (const float*)d_in[6];
    const float* b1    = (const float*)d_in[7];
    const float* W2    = (const float*)d_in[8];
    const float* b2    = (const float*)d_in[9];
    const float* Wf    = (const float*)d_in[10];
    const float* bfv   = (const float*)d_in[11];
    const int* sidx    = (const int*)d_in[12];
    const int* eidx    = (const int*)d_in[13];
    const int* gid     = (const int*)d_in[14];
    const int* spk     = (const int*)d_in[15];
    float* out = (float*)d_out;

    char* ws = (char*)d_ws;
    short* W1T     = (short*)(ws + OFF_W1T);
    short* WfT     = (short*)(ws + OFF_WFT);
    short* cwbf    = (short*)(ws + OFF_CWBF);
    uint8_t* W1c8  = (uint8_t*)(ws + OFF_W1C8);
    float* w2p     = (float*)(ws + OFF_W2P);
    float* b1p     = (float*)(ws + OFF_B1P);
    float* Cg      = (float*)(ws + OFF_CG);
    short* Ftabbf  = (short*)(ws + OFF_FTABBF);
    short* g_bf    = (short*)(ws + OFF_GBF);
    short* tmpbf   = (short*)(ws + OFF_TMPBF);
    float* ant     = (float*)(ws + OFF_ANT);
    float* bsc     = (float*)(ws + OFF_BSC);
    int*   bjj     = (int*)(ws + OFF_BJ);
    int*   fcode   = (int*)(ws + OFF_FC);
    short* AB0bf   = (short*)(ws + OFF_AB0);
    float* saccp   = (float*)(ws + OFF_SACCP);
    short* G1bf    = (short*)(ws + OFF_G1BF);
    short* G2bf    = (short*)(ws + OFF_G2BF);
    short* gnew    = (short*)(ws + OFF_GNEW);
    uint8_t* P     = (uint8_t*)(ws + OFF_P);

    // 1. prep
    prep_all_kernel<<<3824, 256, 0, stream>>>(W1, Wf, cW, W2, b1, gene, diste, spke, g_i,
                                              W1T, WfT, W1c8, cwbf, w2p, b1p, Cg, Ftabbf, g_bf);
    // 2. AB0(t=0) + coarse1 + G1 + G2 (merged, all independent)
    ab0_coarse1_kernel<<<224, 256, 0, stream>>>(g_bf, W1T, AB0bf, cwbf, tmpbf,
                                                WfT, G1bf, G2bf, gid, Cg, b1p);
    // 3. coarse2: ant = tmp @ g^T
    gemm_bt<0><<<dim3(8, 8, 1), 256, 0, stream>>>(
        tmpbf, 512, g_bf, 512, ant, 1024, 512, 0, 0, nullptr, nullptr, nullptr);
    // 4. exact top-50 + features + P(t=0) fill
    topk_kernel<<<1024, 256, 0, stream>>>(ant, ms, sidx, eidx, spk, g_bf, bsc, bjj, fcode, P);
    // 5. fused score t=0
    fused_score_kernel<<<dim3(8, 400), 256, 0, stream>>>(
        P, W1c8, bjj, fcode, AB0bf, Ftabbf, w2p, saccp);
    // 6. softmax + gate update (gate GEMM algebraically folded via G1/G2)
    softmax_gate_kernel<<<1024, 256, 0, stream>>>(saccp, b2, bsc, bjj, g_bf,
                                                  G1bf, G2bf, bfv, gnew);
    // 7. AB0(t=1) from gnew + pairprod(t=1) (merged, independent)
    ab0_pairprod_kernel<<<3328, 256, 0, stream>>>(gnew, W1T, AB0bf, gid, Cg, b1p, bjj, P);
    // 8. fused score t=1
    fused_score_kernel<<<dim3(8, 400), 256, 0, stream>>>(
        P, W1c8, bjj, fcode, AB0bf, Ftabbf, w2p, saccp);
    // 9. finalize
    finalize_kernel<<<204, 256, 0, stream>>>(saccp, b2, bsc, out);
}